// Round 3
// baseline (2961.781 us; speedup 1.0000x reference)
//
#include <hip/hip_runtime.h>
#include <hip/hip_bf16.h>

// ---- problem constants ----
#define B_   16384
#define H_   128
#define C_   4
#define L_   6
#define O_   1024
#define G3H  384
#define CB   (C_ * B_)
#define CBH  (C_ * B_ * H_)

typedef __hip_bfloat16 bf16;
using bf16x8  = __attribute__((ext_vector_type(8))) __bf16;
using floatx4 = __attribute__((ext_vector_type(4))) float;

__device__ __forceinline__ bf16 f2bf(float x) { return __float2bfloat16(x); }
__device__ __forceinline__ float bf2f(bf16 x) { return __bfloat162float(x); }
__device__ __forceinline__ void store_val(float* p, float v) { *p = v; }
__device__ __forceinline__ void store_val(bf16* p, float v) { *p = f2bf(v); }

__device__ __forceinline__ floatx4 mfma16(bf16x8 a, bf16x8 b, floatx4 c) {
  return __builtin_amdgcn_mfma_f32_16x16x32_bf16(a, b, c, 0, 0, 0);
}

// fragment loaders: 8 consecutive K elements
__device__ __forceinline__ bf16x8 load8(const bf16* p) { return *(const bf16x8*)p; }
__device__ __forceinline__ bf16x8 load8(const float* p) {
  bf16x8 r;
#pragma unroll
  for (int i = 0; i < 8; ++i) r[i] = (__bf16)p[i];
  return r;
}

__device__ __forceinline__ float wave_sum(float x) {
#pragma unroll
  for (int off = 32; off; off >>= 1) x += __shfl_xor(x, off);
  return x;
}

// f32 -> bf16 conversion (weights, once per launch)
__global__ __launch_bounds__(256) void cvt_kernel(const float* __restrict__ in,
                                                  bf16* __restrict__ out, long n) {
  long i = (long)blockIdx.x * 256 + threadIdx.x;
  if (i < n) out[i] = f2bf(in[i]);
}

// ---------------------------------------------------------------------------
// Generic GEMM: out[r, n] = sum_k A[r,k] * W[n,k] + bias[n]
// A: R x 128 (f32 or bf16).  W: (batch) x N x 128 bf16.  batch = r / rows_per_batch.
// Fragment layouts (m89-verified):
//   A/B frag: m|n = lane&15, k = (lane>>4)*8 + j
//   C/D:      col(n) = lane&15, row(m) = (lane>>4)*4 + reg
// ---------------------------------------------------------------------------
template <typename AT, typename OutT>
__global__ __launch_bounds__(256) void gemm_bt(const AT* __restrict__ A,
                                               const bf16* __restrict__ W,
                                               const float* __restrict__ bias,
                                               OutT* __restrict__ out,
                                               int N, int rows_per_batch,
                                               long wstride, long bstride) {
  const int wave = threadIdx.x >> 6;
  const int lane = threadIdx.x & 63;
  const int m0   = blockIdx.x * 16;
  const int n0   = blockIdx.y * 64 + wave * 16;
  const int sub  = lane & 15;
  const int quad = lane >> 4;
  const int batch = m0 / rows_per_batch;
  const bf16*  Wb = W + (long)batch * wstride;
  const float* Bi = bias + (long)batch * bstride;

  const AT*   Ap = A + (long)(m0 + sub) * 128 + quad * 8;
  const bf16* Wp = Wb + (long)(n0 + sub) * 128 + quad * 8;

  floatx4 acc = {0.f, 0.f, 0.f, 0.f};
#pragma unroll
  for (int kc = 0; kc < 4; ++kc) {
    acc = mfma16(load8(Ap + kc * 32), load8(Wp + kc * 32), acc);
  }

  const int col = n0 + sub;
  const float bv = Bi[col];
#pragma unroll
  for (int r = 0; r < 4; ++r) {
    long row = m0 + quad * 4 + r;
    store_val(&out[row * (long)N + col], acc[r] + bv);
  }
}

// x0[b,:] = bf16(emb[tokens[b],:])
__global__ __launch_bounds__(128) void embed_kernel(const int* __restrict__ tok,
                                                    const float* __restrict__ emb,
                                                    bf16* __restrict__ x0) {
  const int b = blockIdx.x;
  x0[(long)b * 128 + threadIdx.x] = f2bf(emb[(long)tok[b] * 128 + threadIdx.x]);
}

// layer-0 cells 1..3: gi = bih0[c] broadcast
__global__ __launch_bounds__(256) void fill_gi0(bf16* __restrict__ gi,
                                                const float* __restrict__ bih0) {
  long idx = (long)blockIdx.x * 256 + threadIdx.x;  // < 3*B*384
  int gcol = (int)(idx % G3H);
  long r = idx / G3H;  // 0..3B-1
  int c = 1 + (int)(r / B_);
  gi[((long)B_ + r) * G3H + gcol] = f2bf(bih0[c * G3H + gcol]);
}

// ---------------------------------------------------------------------------
// Fused: gh = h @ whh^T + bhh (MFMA, LDS f32), then GRU -> hn (f32, d_out)
// One block = 16 rows; 4 waves x 6 col-tiles of 16.
// ---------------------------------------------------------------------------
__global__ __launch_bounds__(256) void gru_fused(const float* __restrict__ h,
                                                 const bf16* __restrict__ whh,
                                                 const float* __restrict__ bhh,
                                                 const bf16* __restrict__ gi,
                                                 float* __restrict__ hn) {
  __shared__ float gh_s[16 * 388];
  const int wave = threadIdx.x >> 6, lane = threadIdx.x & 63;
  const int sub = lane & 15, quad = lane >> 4;
  const int m0 = blockIdx.x * 16;
  const int cell = m0 / B_;
  const bf16*  Wc = whh + (long)cell * G3H * H_;
  const float* bc = bhh + cell * G3H;

  const float* Ap = h + (long)(m0 + sub) * H_ + quad * 8;
  bf16x8 a0 = load8(Ap), a1 = load8(Ap + 32), a2 = load8(Ap + 64), a3 = load8(Ap + 96);

#pragma unroll
  for (int t = 0; t < 6; ++t) {
    const int n0 = wave * 96 + t * 16;
    const bf16* Wp = Wc + (long)(n0 + sub) * H_ + quad * 8;
    floatx4 acc = {0.f, 0.f, 0.f, 0.f};
    acc = mfma16(a0, load8(Wp), acc);
    acc = mfma16(a1, load8(Wp + 32), acc);
    acc = mfma16(a2, load8(Wp + 64), acc);
    acc = mfma16(a3, load8(Wp + 96), acc);
    const int col = n0 + sub;
    const float bv = bc[col];
#pragma unroll
    for (int r = 0; r < 4; ++r) gh_s[(quad * 4 + r) * 388 + col] = acc[r] + bv;
  }
  __syncthreads();

  // GRU elementwise: thread -> (row = tid>>4, 8 consecutive cols)
  const int row = threadIdx.x >> 4;
  const int cb = (threadIdx.x & 15) * 8;
  const long grow = m0 + row;
  const bf16*  gir = gi + grow * G3H;
  const float* hr = h + grow * H_;
  float* outr = hn + grow * H_;
#pragma unroll
  for (int j = 0; j < 8; ++j) {
    const int c = cb + j;
    float ir = bf2f(gir[c]), iz = bf2f(gir[128 + c]), inn = bf2f(gir[256 + c]);
    float hrv = gh_s[row * 388 + c], hz = gh_s[row * 388 + 128 + c],
          hnn = gh_s[row * 388 + 256 + c];
    float r = 1.f / (1.f + __expf(-(ir + hrv)));
    float z = 1.f / (1.f + __expf(-(iz + hz)));
    float n = tanhf(inn + r * hnn);
    outr[c] = (1.f - z) * n + z * hr[c];
  }
}

// attention over C=4 cells; block = one batch elem, 128 thr = 4 heads x 32 dims
__global__ __launch_bounds__(128) void attn_kernel(const bf16* __restrict__ qkv,
                                                   bf16* __restrict__ o) {
  const int b = blockIdx.x;
  const int nh = threadIdx.x >> 5;
  const int d = threadIdx.x & 31;
  float q[C_], k[C_], v[C_];
#pragma unroll
  for (int c = 0; c < C_; ++c) {
    long base = ((long)c * B_ + b) * G3H + nh * 32 + d;
    q[c] = bf2f(qkv[base]);
    k[c] = bf2f(qkv[base + 128]);
    v[c] = bf2f(qkv[base + 256]);
  }
  float a[C_][C_];
#pragma unroll
  for (int qc = 0; qc < C_; ++qc) {
#pragma unroll
    for (int kc = 0; kc < C_; ++kc) {
      float p = q[qc] * k[kc];
#pragma unroll
      for (int off = 16; off; off >>= 1) p += __shfl_xor(p, off, 32);
      a[qc][kc] = p * 0.17677669529663687f;  // 1/sqrt(32)
    }
  }
#pragma unroll
  for (int qc = 0; qc < C_; ++qc) {
    float m = fmaxf(fmaxf(a[qc][0], a[qc][1]), fmaxf(a[qc][2], a[qc][3]));
    float s = 0.f;
#pragma unroll
    for (int kc = 0; kc < C_; ++kc) { a[qc][kc] = __expf(a[qc][kc] - m); s += a[qc][kc]; }
    float inv = 1.f / s;
    float ov = 0.f;
#pragma unroll
    for (int kc = 0; kc < C_; ++kc) ov += a[qc][kc] * v[kc];
    o[((long)qc * B_ + b) * H_ + nh * 32 + d] = f2bf(ov * inv);
  }
}

// ---------------------------------------------------------------------------
// Fused: o2 = o @ aoutw^T + aoutb (MFMA, LDS f32), LayerNorm, gate, blend.
// One block = 16 rows; 4 waves x 2 col-tiles; then each wave LNs 4 rows.
// hn (f32, d_out) read + overwritten in place.
// ---------------------------------------------------------------------------
__global__ __launch_bounds__(256) void oproj_ln_gate(const bf16* __restrict__ o,
                                                     const bf16* __restrict__ w,
                                                     const float* __restrict__ bias,
                                                     const float* __restrict__ g,
                                                     const float* __restrict__ bb,
                                                     const float* __restrict__ gatew,
                                                     const float* __restrict__ gateb,
                                                     float* __restrict__ hn) {
  __shared__ float o_s[16 * 132];
  const int wave = threadIdx.x >> 6, lane = threadIdx.x & 63;
  const int sub = lane & 15, quad = lane >> 4;
  const int m0 = blockIdx.x * 16;

  const bf16* Ap = o + (long)(m0 + sub) * H_ + quad * 8;
  bf16x8 a0 = load8(Ap), a1 = load8(Ap + 32), a2 = load8(Ap + 64), a3 = load8(Ap + 96);

#pragma unroll
  for (int t = 0; t < 2; ++t) {
    const int n0 = wave * 32 + t * 16;
    const bf16* Wp = w + (long)(n0 + sub) * H_ + quad * 8;
    floatx4 acc = {0.f, 0.f, 0.f, 0.f};
    acc = mfma16(a0, load8(Wp), acc);
    acc = mfma16(a1, load8(Wp + 32), acc);
    acc = mfma16(a2, load8(Wp + 64), acc);
    acc = mfma16(a3, load8(Wp + 96), acc);
    const int col = n0 + sub;
    const float bv = bias[col];
#pragma unroll
    for (int r = 0; r < 4; ++r) o_s[(quad * 4 + r) * 132 + col] = acc[r] + bv;
  }
  __syncthreads();

#pragma unroll
  for (int rr = 0; rr < 4; ++rr) {
    const int row = wave * 4 + rr;
    const int j1 = lane, j2 = lane + 64;
    float v1 = o_s[row * 132 + j1], v2 = o_s[row * 132 + j2];
    float mu = wave_sum(v1 + v2) * (1.f / 128.f);
    float d1 = v1 - mu, d2 = v2 - mu;
    float var = wave_sum(d1 * d1 + d2 * d2) * (1.f / 128.f);
    float rs = rsqrtf(var + 1e-5f);
    float m1 = d1 * rs * g[j1] + bb[j1];
    float m2 = d2 * rs * g[j2] + bb[j2];
    const long grow = m0 + row;
    float h1 = hn[grow * H_ + j1], h2 = hn[grow * H_ + j2];
    float gp = h1 * gatew[j1] + m1 * gatew[128 + j1] +
               h2 * gatew[j2] + m2 * gatew[128 + j2];
    float gt = 1.f / (1.f + __expf(-(wave_sum(gp) + gateb[0])));
    hn[grow * H_ + j1] = (1.f - gt) * h1 + gt * m1;
    hn[grow * H_ + j2] = (1.f - gt) * h2 + gt * m2;
  }
}

extern "C" void kernel_launch(void* const* d_in, const int* in_sizes, int n_in,
                              void* d_out, int out_size, void* d_ws, size_t ws_size,
                              hipStream_t stream) {
  const int*   tokens = (const int*)d_in[0];
  const float* h      = (const float*)d_in[1];
  const float* emb    = (const float*)d_in[2];
  const float* wih0c0 = (const float*)d_in[3];
  const float* bih0   = (const float*)d_in[5];
  const float* whh0   = (const float*)d_in[6];
  const float* bhh0   = (const float*)d_in[7];
  const float* wih    = (const float*)d_in[8];
  const float* whh    = (const float*)d_in[9];
  const float* bih    = (const float*)d_in[10];
  const float* bhh    = (const float*)d_in[11];
  const float* ainw   = (const float*)d_in[12];
  const float* ainb   = (const float*)d_in[13];
  const float* aoutw  = (const float*)d_in[14];
  const float* aoutb  = (const float*)d_in[15];
  const float* lng    = (const float*)d_in[16];
  const float* lnb    = (const float*)d_in[17];
  const float* gw     = (const float*)d_in[18];
  const float* gb     = (const float*)d_in[19];
  const float* headw  = (const float*)d_in[20];
  const float* headb  = (const float*)d_in[21];

  float* y_out  = (float*)d_out;                 // (B, O)
  float* hn_out = (float*)d_out + (long)B_ * O_; // (L, C, B, H)

  // workspace layout (bf16 elements), ~70 MiB total
  bf16* ws = (bf16*)d_ws;
  bf16* bufA = ws;                          // CB*384 = 48 MiB
  bf16* bufO = bufA + (long)CB * G3H;       // CB*128 = 16 MiB
  bf16* x0   = bufO;                        // aliases bufO (dead by first attn)
  bf16* wp   = bufO + (long)CB * H_;
  bf16* wih0bf  = wp;                  wp += 49152;   // 384*128
  bf16* whh0bf  = wp;                  wp += 196608;  // 4*384*128
  bf16* wihbf   = wp;                  wp += 983040;  // 5*4*384*128
  bf16* whhbf   = wp;                  wp += 983040;
  bf16* ainwbf  = wp;                  wp += 294912;  // 6*384*128
  bf16* aoutwbf = wp;                  wp += 98304;   // 6*128*128
  bf16* headwbf = wp;                  wp += 131072;  // 1024*128

  dim3 blk(256);
  auto cvt = [&](const float* src, bf16* dst, long n) {
    cvt_kernel<<<(int)((n + 255) / 256), blk, 0, stream>>>(src, dst, n);
  };
  cvt(wih0c0, wih0bf, 49152);
  cvt(whh0, whh0bf, 196608);
  cvt(wih, wihbf, 983040);
  cvt(whh, whhbf, 983040);
  cvt(ainw, ainwbf, 294912);
  cvt(aoutw, aoutwbf, 98304);
  cvt(headw, headwbf, 131072);

  embed_kernel<<<B_, 128, 0, stream>>>(tokens, emb, x0);

  for (int l = 0; l < L_; ++l) {
    float* hn_l = hn_out + (long)l * CBH;
    const float* hl = h + (long)l * CBH;

    // gi -> bufA (bf16)
    if (l == 0) {
      gemm_bt<bf16, bf16><<<dim3(B_ / 16, G3H / 64), blk, 0, stream>>>(
          x0, wih0bf, bih0, bufA, G3H, B_, 0, 0);
      fill_gi0<<<(3 * B_ * G3H) / 256, blk, 0, stream>>>(bufA, bih0);
    } else {
      gemm_bt<float, bf16><<<dim3(CB / 16, G3H / 64), blk, 0, stream>>>(
          hn_out + (long)(l - 1) * CBH, wihbf + (long)(l - 1) * C_ * G3H * H_,
          bih + (long)(l - 1) * C_ * G3H, bufA, G3H, B_, (long)G3H * H_, G3H);
    }

    // gh GEMM + GRU fused -> hn_l (f32 in d_out, pre-gate value)
    const bf16*  whl = (l == 0) ? whh0bf : whhbf + (long)(l - 1) * C_ * G3H * H_;
    const float* bhl = (l == 0) ? bhh0 : bhh + (long)(l - 1) * C_ * G3H;
    gru_fused<<<CB / 16, blk, 0, stream>>>(hl, whl, bhl, bufA, hn_l);

    // qkv -> bufA (bf16)
    gemm_bt<float, bf16><<<dim3(CB / 16, G3H / 64), blk, 0, stream>>>(
        hn_l, ainwbf + (long)l * G3H * H_, ainb + (long)l * G3H, bufA, G3H, CB, 0, 0);

    // attention -> bufO (bf16)
    attn_kernel<<<B_, 128, 0, stream>>>(bufA, bufO);

    // out-proj + LN + gate + blend -> hn_l (final, f32)
    oproj_ln_gate<<<CB / 16, blk, 0, stream>>>(
        bufO, aoutwbf + (long)l * H_ * H_, aoutb + (long)l * H_,
        lng + l * H_, lnb + l * H_, gw + l * 2 * H_, gb + l, hn_l);
  }

  // head: y = h_n[5, c=0] @ head_w^T + head_b
  gemm_bt<float, float><<<dim3(B_ / 16, O_ / 64), blk, 0, stream>>>(
      hn_out + (long)5 * CBH, headwbf, headb, y_out, O_, B_, 0, 0);
}